// Round 5
// baseline (140.875 us; speedup 1.0000x reference)
//
#include <hip/hip_runtime.h>

#define N_NODES 50000
#define N_EDGES 800000
#define D 96
#define D4 (D / 4)        // 24 float4 per row

#define RL 12             // bf16 row = 96*2B = 12 uint4 per node row
#define HPAD 13           // LDS h-row stride in uint4 (kills bank conflicts)

// ---- counting-sort geometry ----
#define NB 196            // buckets of 256 nodes (ceil(50000/256))
#define ECAP 5120         // per-bucket dst-edge capacity (mean 4096, +16 sigma)
#define SCAP 5120         // per-bucket src-entry capacity (same stats)
#define CCAP 6144         // per-bucket padded-CSR capacity u16 (mean ~5050, +16 sigma)
#define PA_BLOCKS 400
#define PA_CHUNK 2000     // 400 * 2000 = 800000 exact
#define WPREP_TB 5        // tail blocks of sortB grid for WT prep (5*1024 >= 4608)

typedef __attribute__((ext_vector_type(8))) short short8;
typedef __attribute__((ext_vector_type(4))) float floatx4;

__device__ __forceinline__ short8 as_short8(uint4 u) { return *(short8*)&u; }

// bf16 RTNE pack: a -> low 16, b -> high 16.
__device__ __forceinline__ unsigned bf16pack(float a, float b) {
    unsigned ua = __float_as_uint(a);
    unsigned ub = __float_as_uint(b);
    ua = (ua + 0x7FFFu + ((ua >> 16) & 1u)) >> 16;       // RTNE
    ub = (ub + 0x7FFFu + ((ub >> 16) & 1u)) & 0xFFFF0000u;
    return ua | ub;
}

// Stage 1a: dual-key bucket partition (UNCHANGED — verified R3/R4). Edges to
// dst-buckets (ebuf, (dst<<16)|src) AND src values to src-buckets (sbuf, u16)
// via one LDS counting sort with a fused 512-wide dual scan. No global data
// atomics.
__global__ void __launch_bounds__(1024) sortA_kernel(
        const int* __restrict__ src, const int* __restrict__ dst,
        unsigned* __restrict__ gcur,       // [2*NB]: dst cursors | src cursors
        unsigned* __restrict__ ebuf, unsigned short* __restrict__ sbuf) {
    __shared__ unsigned raw[PA_CHUNK];          // 8 KB
    __shared__ unsigned ord[PA_CHUNK];          // 8 KB
    __shared__ unsigned short sord[PA_CHUNK];   // 4 KB
    __shared__ unsigned hist[512];   // [0..255] dst-buckets, [256..511] src-buckets
    __shared__ unsigned sc[512], lstart[512], cur[512], gbase[512];
    int t = threadIdx.x;
    int e0 = blockIdx.x * PA_CHUNK;
    if (t < 512) hist[t] = 0;
    __syncthreads();
    for (int i = t; i < PA_CHUNK; i += 1024) {
        int s = src[e0 + i];
        int d = dst[e0 + i];
        raw[i] = ((unsigned)d << 16) | (unsigned)s;
        atomicAdd(&hist[d >> 8], 1u);
        atomicAdd(&hist[256 + (s >> 8)], 1u);
    }
    __syncthreads();
    if (t < 512) sc[t] = hist[t];
    __syncthreads();
    for (int o = 1; o < 256; o <<= 1) {      // two Hillis-Steele scans, fused
        unsigned v = 0;
        if (t < 512 && (t & 255) >= o) v = sc[t - o];
        __syncthreads();
        if (t < 512 && (t & 255) >= o) sc[t] += v;
        __syncthreads();
    }
    if (t < 512) {
        unsigned ls = sc[t] - hist[t];       // exclusive
        lstart[t] = ls;
        cur[t] = ls;
        if ((t & 255) < NB)
            gbase[t] = atomicAdd(&gcur[(t >> 8) * NB + (t & 255)], hist[t]);
    }
    __syncthreads();
    for (int i = t; i < PA_CHUNK; i += 1024) {   // LDS scatter into bucket order
        unsigned r = raw[i];
        unsigned p = atomicAdd(&cur[r >> 24], 1u);        // dst bucket
        ord[p] = r;
        unsigned s = r & 0xFFFFu;
        unsigned q = atomicAdd(&cur[256 + (s >> 8)], 1u); // src bucket
        sord[q] = (unsigned short)s;
    }
    __syncthreads();
    for (int i = t; i < PA_CHUNK; i += 1024) {   // coalesced-run copy-out
        unsigned r = ord[i];
        unsigned bd = r >> 24;
        unsigned pos = gbase[bd] + ((unsigned)i - lstart[bd]);
        if (pos < ECAP) ebuf[bd * ECAP + pos] = r;
        unsigned s = sord[i];
        unsigned bs = 256 + (s >> 8);
        unsigned pos2 = gbase[bs] + ((unsigned)i - lstart[bs]);
        if (pos2 < SCAP) sbuf[(size_t)(bs - 256) * SCAP + pos2] = (unsigned short)s;
    }
}

// Stage 1b (single-pass): 196 full-bucket blocks + 5 WT-prep tails.
// One ebuf read (staged in eb[], vs R4's two global passes), 3-barrier
// shfl scan (vs R3's 16-barrier Hillis-Steele), no half-split divergence.
// Keeps R4's conv fusion: sfeat rows for the 256 owned nodes produced here.
__global__ void __launch_bounds__(1024) sortB_kernel(
        const unsigned* __restrict__ gcur, const unsigned* __restrict__ ebuf,
        const unsigned short* __restrict__ sbuf,
        const float4* __restrict__ feat4, const float* __restrict__ W,
        unsigned* __restrict__ WT32,
        int* __restrict__ deg_in, int* __restrict__ off,
        unsigned short* __restrict__ csr, uint4* __restrict__ sfeat) {
    int blk = blockIdx.x;
    if (blk >= NB) {   // WT prep tail
        int t2 = (blk - NB) * 1024 + threadIdx.x;
        if (t2 >= D * (D / 2)) return;
        int n = t2 / (D / 2);
        int j = t2 - n * (D / 2);
        float w0 = W[(2 * j) * D + n];
        float w1 = W[(2 * j + 1) * D + n];
        WT32[n * (D / 2) + j] = bf16pack(w0, w1);
        return;
    }
    __shared__ unsigned eb[ECAP];              // 20 KB
    __shared__ unsigned short csr_l[CCAP];     // 12 KB
    __shared__ unsigned dcount[256], dcur[256], scount[256], wsum[4];
    __shared__ unsigned tot_s;
    int b = blk;
    int t = threadIdx.x;
    unsigned cntd = gcur[b];      if (cntd > ECAP) cntd = ECAP;
    unsigned cnts = gcur[NB + b]; if (cnts > SCAP) cnts = SCAP;
    if (t < 256) { dcount[t] = 0; scount[t] = 0; }
    __syncthreads();
    const unsigned* __restrict__ sg = ebuf + (size_t)b * ECAP;
    for (int i = t; i < (int)cntd; i += 1024) {
        unsigned r = sg[i];
        eb[i] = r;
        atomicAdd(&dcount[(r >> 16) & 255u], 1u);
    }
    const unsigned short* __restrict__ ss = sbuf + (size_t)b * SCAP;
    for (int i = t; i < (int)cnts; i += 1024)
        atomicAdd(&scount[ss[i] & 255u], 1u);
    __syncthreads();
    // ---- 3-barrier shfl scan of 8-padded sizes (threads 0..255 = 4 waves) ----
    unsigned pad = 0, incl = 0;
    if (t < 256) {
        pad = (dcount[t] + 7u) & ~7u;
        incl = pad;
        int lane = t & 63;
#pragma unroll
        for (int st = 1; st < 64; st <<= 1) {
            unsigned u = __shfl_up(incl, st, 64);
            if (lane >= st) incl += u;
        }
        if (lane == 63) wsum[t >> 6] = incl;
    }
    __syncthreads();
    if (t < 256) {
        int w = t >> 6;
        unsigned base = 0;
        for (int k = 0; k < w; ++k) base += wsum[k];
        incl += base;
        unsigned ex = incl - pad;               // exclusive padded
        dcur[t] = ex;
        if (t == 255) tot_s = incl;
        int n = b * 256 + t;
        if (n < N_NODES) {
            deg_in[n] = (int)dcount[t];
            off[n] = b * CCAP + (int)ex;
        }
    }
    __syncthreads();
    // ---- CSR scatter from LDS stage ----
    for (int i = t; i < (int)cntd; i += 1024) {
        unsigned r = eb[i];
        unsigned p = atomicAdd(&dcur[(r >> 16) & 255u], 1u);
        if (p < CCAP) csr_l[p] = (unsigned short)(r & 0xFFFFu);
    }
    __syncthreads();
    unsigned tot = tot_s;
    if (tot > CCAP) tot = CCAP;
    unsigned* __restrict__ og = (unsigned*)(csr + (size_t)b * CCAP);
    const unsigned* __restrict__ cl = (const unsigned*)csr_l;
    for (int i = t; i < (int)(tot >> 1); i += 1024) og[i] = cl[i];
    // ---- fused conv: sfeat rows for the 256 owned nodes ----
    for (int r2 = t; r2 < 256 * RL; r2 += 1024) {
        int nl = r2 / RL;
        int lane = r2 - nl * RL;
        int n = b * 256 + nl;
        if (n < N_NODES) {
            float c = rsqrtf(fmaxf((float)scount[nl], 1.0f));
            float4 a = feat4[(size_t)n * D4 + lane * 2];
            float4 bb = feat4[(size_t)n * D4 + lane * 2 + 1];
            uint4 o;
            o.x = bf16pack(a.x * c, a.y * c);
            o.y = bf16pack(a.z * c, a.w * c);
            o.z = bf16pack(bb.x * c, bb.y * c);
            o.w = bf16pack(bb.z * c, bb.w * c);
            sfeat[(size_t)n * RL + lane] = o;
        }
    }
}

// Stage 2 (fused gather+MFMA, 2-team degree-split): 384 threads =
// 16 nodes x 12 lanes x 2 teams. Team t accumulates neighbor chunks
// [8c,8c+8) with c&1==t (balanced +-8, 16B-aligned idx loads); team 0
// parks f32 partials in LDS, team 1 combines+scales+packs the bf16 A-tile.
// Halves the serial latency chain AND the max-deg wave divergence vs the
// single-team R3/R4 version. MFMA: 6 waves x 1 col-tile each.
// Layouts (m89/m91-verified): A[m=lane&15][k=quad*8+j]; B[k=quad*8+j][n=lane&15];
// D col=lane&15, row=quad*4+reg.
__global__ void __launch_bounds__(384) gather_mm_kernel(
        const float4* __restrict__ feat4, const uint4* __restrict__ sfeat,
        const int* __restrict__ deg_in, const int* __restrict__ off,
        const unsigned short* __restrict__ csr, const uint4* __restrict__ wt4,
        const float* __restrict__ bias, float* __restrict__ out) {
    __shared__ float shp[16][D];      // 6 KB team-0 f32 partials
    __shared__ uint4 sh[16 * HPAD];   // 3.25 KB bf16 A-tile
    int tid = threadIdx.x;
    int team = (tid >= 192) ? 1 : 0;
    int r = tid - team * 192;
    int g = r / RL;              // node 0..15
    int lane = r - g * RL;       // uint4 index 0..11 (8 bf16)
    int n = blockIdx.x * 16 + g; // 3125*16 = 50000 exact
    int deg = deg_in[n];
    float acc[8] = {};
    if (deg == 0) {
        if (team == 0) {   // passthrough: h = feat (isolated node)
            float4 a = feat4[(size_t)n * D4 + lane * 2];
            float4 b = feat4[(size_t)n * D4 + lane * 2 + 1];
            acc[0] = a.x; acc[1] = a.y; acc[2] = a.z; acc[3] = a.w;
            acc[4] = b.x; acc[5] = b.y; acc[6] = b.z; acc[7] = b.w;
        }
    } else {
        const unsigned short* __restrict__ bk = csr + off[n];
        const uint4* __restrict__ sf = sfeat + lane;
#define ACC8(v)  { \
        acc[0] += __uint_as_float((v).x << 16); \
        acc[1] += __uint_as_float((v).x & 0xFFFF0000u); \
        acc[2] += __uint_as_float((v).y << 16); \
        acc[3] += __uint_as_float((v).y & 0xFFFF0000u); \
        acc[4] += __uint_as_float((v).z << 16); \
        acc[5] += __uint_as_float((v).z & 0xFFFF0000u); \
        acc[6] += __uint_as_float((v).w << 16); \
        acc[7] += __uint_as_float((v).w & 0xFFFF0000u); }
        for (int i = team * 8; i + 8 <= deg; i += 16) {
            uint4 idx = *(const uint4*)(bk + i);   // 8 u16 indices, 16B-aligned
            unsigned s0 = idx.x & 0xFFFFu, s1 = idx.x >> 16;
            unsigned s2 = idx.y & 0xFFFFu, s3 = idx.y >> 16;
            unsigned s4 = idx.z & 0xFFFFu, s5 = idx.z >> 16;
            unsigned s6 = idx.w & 0xFFFFu, s7 = idx.w >> 16;
            uint4 v0 = sf[(size_t)s0 * RL];
            uint4 v1 = sf[(size_t)s1 * RL];
            uint4 v2 = sf[(size_t)s2 * RL];
            uint4 v3 = sf[(size_t)s3 * RL];
            uint4 v4 = sf[(size_t)s4 * RL];
            uint4 v5 = sf[(size_t)s5 * RL];
            uint4 v6 = sf[(size_t)s6 * RL];
            uint4 v7 = sf[(size_t)s7 * RL];
            ACC8(v0); ACC8(v1); ACC8(v2); ACC8(v3);
            ACC8(v4); ACC8(v5); ACC8(v6); ACC8(v7);
        }
        int ts = deg & ~7;                       // tail chunk [ts, deg)
        if (((ts >> 3) & 1) == team) {
            for (int j = ts; j < deg; ++j) {
                uint4 v = sf[(size_t)bk[j] * RL];
                ACC8(v);
            }
        }
#undef ACC8
    }
    if (team == 0) {
#pragma unroll
        for (int j = 0; j < 8; ++j) shp[g][lane * 8 + j] = acc[j];
    }
    __syncthreads();
    if (team == 1) {
        float cj = (deg > 0) ? rsqrtf((float)deg) : 1.0f;
        float s0 = (shp[g][lane * 8 + 0] + acc[0]) * cj;
        float s1 = (shp[g][lane * 8 + 1] + acc[1]) * cj;
        float s2 = (shp[g][lane * 8 + 2] + acc[2]) * cj;
        float s3 = (shp[g][lane * 8 + 3] + acc[3]) * cj;
        float s4 = (shp[g][lane * 8 + 4] + acc[4]) * cj;
        float s5 = (shp[g][lane * 8 + 5] + acc[5]) * cj;
        float s6 = (shp[g][lane * 8 + 6] + acc[6]) * cj;
        float s7 = (shp[g][lane * 8 + 7] + acc[7]) * cj;
        uint4 o;
        o.x = bf16pack(s0, s1);
        o.y = bf16pack(s2, s3);
        o.z = bf16pack(s4, s5);
        o.w = bf16pack(s6, s7);
        sh[g * HPAD + lane] = o;
    }
    __syncthreads();
    // ---- MFMA phase: 6 waves, one 16-col tile each ----
    int wave = tid >> 6;
    int lane64 = tid & 63;
    int m = lane64 & 15, quad = lane64 >> 4;
    short8 a0 = as_short8(sh[m * HPAD + quad]);       // k = 0..31
    short8 a1 = as_short8(sh[m * HPAD + 4 + quad]);   // k = 32..63
    short8 a2 = as_short8(sh[m * HPAD + 8 + quad]);   // k = 64..95
    int nn = wave * 16 + m;
    int wb = nn * RL + quad;
    short8 b0 = as_short8(wt4[wb]);
    short8 b1 = as_short8(wt4[wb + 4]);
    short8 b2 = as_short8(wt4[wb + 8]);
    floatx4 c = {0.f, 0.f, 0.f, 0.f};
    c = __builtin_amdgcn_mfma_f32_16x16x32_bf16(a0, b0, c, 0, 0, 0);
    c = __builtin_amdgcn_mfma_f32_16x16x32_bf16(a1, b1, c, 0, 0, 0);
    c = __builtin_amdgcn_mfma_f32_16x16x32_bf16(a2, b2, c, 0, 0, 0);
    float bs = bias[nn];
    int r_out0 = blockIdx.x * 16 + quad * 4;
#pragma unroll
    for (int rr = 0; rr < 4; ++rr)
        out[(size_t)(r_out0 + rr) * D + nn] = c[rr] + bs;
}

extern "C" void kernel_launch(void* const* d_in, const int* in_sizes, int n_in,
                              void* d_out, int out_size, void* d_ws, size_t ws_size,
                              hipStream_t stream) {
    const float* feat = (const float*)d_in[0];
    const float* W    = (const float*)d_in[1];
    const float* bias = (const float*)d_in[2];
    const int*   src  = (const int*)d_in[3];
    const int*   dst  = (const int*)d_in[4];

    // ws layout (~18.4 MB; every byte rewritten each call or never read):
    //   gcur[2*NB] | deg_in[N] | off[N] |
    //   ebuf u32 [NB][ECAP] 4.0MB | sbuf u16 [NB][SCAP] 2.0MB |
    //   csr u16 [NB][CCAP] 2.4MB | sfeat 9.6MB | WT 18KB
    unsigned*       gcur    = (unsigned*)d_ws;
    int*            deg_in  = (int*)(gcur + 2 * NB);
    int*            off     = deg_in + N_NODES;
    unsigned*       ebuf    = (unsigned*)(off + N_NODES);
    unsigned short* sbuf    = (unsigned short*)(ebuf + (size_t)NB * ECAP);
    unsigned short* csr     = sbuf + (size_t)NB * SCAP;
    uint4*          sfeat   = (uint4*)(csr + (size_t)NB * CCAP);
    unsigned*       WT32    = (unsigned*)(sfeat + (size_t)N_NODES * RL);

    hipMemsetAsync(gcur, 0, 2 * NB * sizeof(unsigned), stream);
    sortA_kernel<<<PA_BLOCKS, 1024, 0, stream>>>(src, dst, gcur, ebuf, sbuf);
    sortB_kernel<<<NB + WPREP_TB, 1024, 0, stream>>>(
        gcur, ebuf, sbuf, (const float4*)feat, W, WT32, deg_in, off, csr, sfeat);
    gather_mm_kernel<<<N_NODES / 16, 384, 0, stream>>>(
        (const float4*)feat, sfeat, deg_in, off, csr, (const uint4*)WT32,
        bias, (float*)d_out);
}